// Round 3
// baseline (683.248 us; speedup 1.0000x reference)
//
#include <hip/hip_runtime.h>

// Problem constants
#define CCH 768
#define NCL 64
#define HWIN 1024                 // 32*32 pixels per batch
#define RES_ELEMS 134217728LL     // 8*64*512*512
#define CODE_ELEMS 6291456LL      // 8*768*32*32
#define CQUADS 1572863LL          // float4 code-copy quads: out[RES+4 .. RES+4+4*CQUADS)
#define COPY_BLOCKS 1536          // 1536*256 threads * 4 quads >= CQUADS
#define DENSE2_BLOCKS 512         // 8 batches * 64 row-chunks (8 rows each)

// ---------------------------------------------------------------------------
// k_norm: 64 blocks: L2-normalize cluster row n=blk into nc_t[c][n] (transposed).
// Block 0 thread 0 also writes loss=0 and the code-copy head/tail scalars.
// ---------------------------------------------------------------------------
__global__ __launch_bounds__(256) void k_norm(const float* __restrict__ clusters,
                                              const float* __restrict__ code,
                                              float* __restrict__ nc_t,
                                              float* __restrict__ out)
{
    int tid = threadIdx.x;
    int n = blockIdx.x;
    __shared__ float red[256];
    float v0 = clusters[n * CCH + tid];
    float v1 = clusters[n * CCH + tid + 256];
    float v2 = clusters[n * CCH + tid + 512];
    red[tid] = v0 * v0 + v1 * v1 + v2 * v2;
    __syncthreads();
    for (int off = 128; off > 0; off >>= 1) {
        if (tid < off) red[tid] += red[tid + off];
        __syncthreads();
    }
    float scale = 1.0f / fmaxf(sqrtf(red[0]), 1e-12f);
    nc_t[(tid      ) * NCL + n] = v0 * scale;
    nc_t[(tid + 256) * NCL + n] = v1 * scale;
    nc_t[(tid + 512) * NCL + n] = v2 * scale;
    if (n == 0 && tid == 0) {
        out[0] = 0.0f;                         // loss accumulator
        out[RES_ELEMS + 1] = code[0];          // code-copy head (3 scalars)
        out[RES_ELEMS + 2] = code[1];
        out[RES_ELEMS + 3] = code[2];
        out[RES_ELEMS + CODE_ELEMS] = code[CODE_ELEMS - 1];   // code-copy tail
    }
}

// ---------------------------------------------------------------------------
// k_assign: 256 blocks x 256 thr. Block handles 32 pixels, full C=768.
// Thread = (cg 0..7: 96 ch) x (ng 0..3: 16 clusters) x (pg 0..7: 4 pixels).
// acc[4 px][16 n] in regs; cluster tile (64 ch x 64 n) staged in LDS per chunk.
// Then LDS tree-reduce over cg, per-pixel argmax, loss atomicAdd.
// ---------------------------------------------------------------------------
__global__ __launch_bounds__(256) void k_assign(const float* __restrict__ code,
                                                const float* __restrict__ nc_t,
                                                int* __restrict__ assign,
                                                float* __restrict__ out)
{
    __shared__ float lds_nc[64 * 64];     // 16 KB staging; reused for reduced dots
    __shared__ float lds_red[8 * 2048];   // 64 KB cg-partials
    __shared__ float lds_sq[8 * 32];      // sumsq partials

    int tid = threadIdx.x;
    int blk = blockIdx.x;
    int cg = tid >> 5;
    int ng = (tid >> 3) & 3;
    int pg = tid & 7;
    int b = blk >> 5;
    int pixb = (blk & 31) << 5;
    const float* codeB = code + (size_t)b * CCH * HWIN + pixb + (pg << 2);

    float acc[4][16];
    #pragma unroll
    for (int p = 0; p < 4; ++p)
        #pragma unroll
        for (int q = 0; q < 16; ++q) acc[p][q] = 0.f;
    float sq0 = 0.f, sq1 = 0.f, sq2 = 0.f, sq3 = 0.f;

    for (int k = 0; k < 12; ++k) {
        __syncthreads();
        const float4* src = (const float4*)(nc_t + k * 4096);
        float4* dst = (float4*)lds_nc;
        #pragma unroll
        for (int i = 0; i < 4; ++i) dst[tid + 256 * i] = src[tid + 256 * i];
        __syncthreads();
        #pragma unroll
        for (int m = 0; m < 8; ++m) {
            int ch = k * 64 + cg * 8 + m;
            float4 f = *(const float4*)(codeB + ch * HWIN);
            sq0 += f.x * f.x; sq1 += f.y * f.y; sq2 += f.z * f.z; sq3 += f.w * f.w;
            const float* ncrow = lds_nc + ((cg * 8 + m) << 6) + (ng << 4);
            #pragma unroll
            for (int q = 0; q < 16; ++q) {
                float w = ncrow[q];
                acc[0][q] += f.x * w;
                acc[1][q] += f.y * w;
                acc[2][q] += f.z * w;
                acc[3][q] += f.w * w;
            }
        }
    }

    #pragma unroll
    for (int p = 0; p < 4; ++p) {
        float4* dstp = (float4*)&lds_red[cg * 2048 + (pg * 4 + p) * 64 + ng * 16];
        dstp[0] = make_float4(acc[p][0],  acc[p][1],  acc[p][2],  acc[p][3]);
        dstp[1] = make_float4(acc[p][4],  acc[p][5],  acc[p][6],  acc[p][7]);
        dstp[2] = make_float4(acc[p][8],  acc[p][9],  acc[p][10], acc[p][11]);
        dstp[3] = make_float4(acc[p][12], acc[p][13], acc[p][14], acc[p][15]);
    }
    if (ng == 0) {
        lds_sq[cg * 32 + pg * 4 + 0] = sq0;
        lds_sq[cg * 32 + pg * 4 + 1] = sq1;
        lds_sq[cg * 32 + pg * 4 + 2] = sq2;
        lds_sq[cg * 32 + pg * 4 + 3] = sq3;
    }
    __syncthreads();

    for (int idx = tid; idx < 2048; idx += 256) {
        float s = 0.f;
        #pragma unroll
        for (int c2 = 0; c2 < 8; ++c2) s += lds_red[c2 * 2048 + idx];
        lds_nc[idx] = s;
    }
    __syncthreads();

    if (tid < 32) {
        float ss = 0.f;
        #pragma unroll
        for (int c2 = 0; c2 < 8; ++c2) ss += lds_sq[c2 * 32 + tid];
        float inv = 1.0f / fmaxf(sqrtf(ss), 1e-12f);
        float best = -1e30f; int bi = 0;
        for (int n = 0; n < 64; ++n) {
            float v = lds_nc[tid * 64 + n];
            if (v > best) { best = v; bi = n; }
        }
        assign[blk * 32 + tid] = bi;
        float l = best * inv;
        l += __shfl_down(l, 16);
        l += __shfl_down(l, 8);
        l += __shfl_down(l, 4);
        l += __shfl_down(l, 2);
        l += __shfl_down(l, 1);
        if (tid == 0) atomicAdd(out, -l * (1.0f / 8192.0f));
    }
}

// ---------------------------------------------------------------------------
// k_dense2: plane-contiguous dense writer.
// Blocks [0,512): block = (b, ic) owns output rows i in [8ic, 8ic+8) for ALL
// 64 planes. n-outer loop writes 16 KB CONTIGUOUS per plane (8 rows x 2 KB)
// before jumping to the next plane (1 MB stride) -> HBM-page-friendly streams,
// one store per output element, no RMW.
// Per-task tables (corner ids, fj, fi) are built once in LDS and hoisted into
// REGISTERS before the n-loop -> hot loop is compare/select/fma + stores only.
//   slot s==0   -> scalar j {0,1,2,511} (alignment head/tail of each 512-row)
//   slot 1..127 -> aligned float4 at j = 4s-1
// Blocks [512, 512+1536): grid-stride float4 copy of code into the out tail.
// ---------------------------------------------------------------------------
__global__ __launch_bounds__(256) void k_dense2(const int* __restrict__ assign,
                                                const float* __restrict__ code,
                                                float* __restrict__ out)
{
    int tid = threadIdx.x;
    int blk = blockIdx.x;

    if (blk >= DENSE2_BLOCKS) {
        // ---- code copy: out[1+RES+e] = code[e], aligned-quad region ----
        long long u = (long long)(blk - DENSE2_BLOCKS) * 256 + tid;
        #pragma unroll
        for (int k = 0; k < 4; ++k) {
            long long q = u + (long long)k * (COPY_BLOCKS * 256);
            if (q < CQUADS) {
                const float* src = code + 3 + 4 * q;          // src misaligned
                float4 v = make_float4(src[0], src[1], src[2], src[3]);
                *(float4*)(out + RES_ELEMS + 4 + 4 * q) = v;  // dst aligned
            }
        }
        return;
    }

    int b  = blk >> 6;       // batch
    int ic = blk & 63;       // 8-row chunk: rows 8ic .. 8ic+7

    __shared__ int    s_as[1024] __attribute__((aligned(16)));  // assign[b], 4 KB
    __shared__ int4   s_jp[128];     // per-slot packed (j0 | j1<<16) x4
    __shared__ float4 s_fj4[128];    // per-slot fj x4
    __shared__ int4   s_pk[1024];    // [r*128+s] packed corner ids x4
    __shared__ float  s_fi[8], s_fi1[8];
    __shared__ int    s_i0[8], s_i1[8];

    // stage assign for this batch (1024 ints)
    *(int4*)&s_as[tid * 4] = *(const int4*)&assign[(b << 10) + tid * 4];

    if (tid < 8) {
        int i = ic * 8 + tid;
        float xi = (i + 0.5f) * 0.0625f - 0.5f;
        float fif = floorf(xi);
        int ii = (int)fif;
        float fi = xi - fif;
        s_fi[tid] = fi;
        s_fi1[tid] = 1.0f - fi;
        s_i0[tid] = (ii < 0 ? 0 : ii) << 5;
        s_i1[tid] = ((ii + 1) > 31 ? 31 : (ii + 1)) << 5;
    }
    if (tid < 128) {
        int s = tid;
        int jl[4];
        if (s == 0) { jl[0] = 0; jl[1] = 1; jl[2] = 2; jl[3] = 511; }
        else { jl[0] = 4 * s - 1; jl[1] = 4 * s; jl[2] = 4 * s + 1; jl[3] = 4 * s + 2; }
        int jp[4]; float fjv[4];
        #pragma unroll
        for (int k = 0; k < 4; ++k) {
            int j = jl[k];
            float xj = (j + 0.5f) * 0.0625f - 0.5f;
            float fjf = floorf(xj);
            int jj = (int)fjf;
            fjv[k] = xj - fjf;
            int j0 = jj < 0 ? 0 : jj;
            int j1 = (jj + 1) > 31 ? 31 : (jj + 1);
            jp[k] = j0 | (j1 << 16);
        }
        s_jp[s]  = make_int4(jp[0], jp[1], jp[2], jp[3]);
        s_fj4[s] = make_float4(fjv[0], fjv[1], fjv[2], fjv[3]);
    }
    __syncthreads();

    // build packed corner-id table: 1024 entries (8 rows x 128 slots)
    #pragma unroll
    for (int e4 = 0; e4 < 4; ++e4) {
        int e = e4 * 256 + tid;
        int r = e >> 7;
        int s = e & 127;
        int4 jp4 = s_jp[s];
        const int* r0 = s_as + s_i0[r];
        const int* r1 = s_as + s_i1[r];
        int jpk[4] = { jp4.x, jp4.y, jp4.z, jp4.w };
        int pk[4];
        #pragma unroll
        for (int k = 0; k < 4; ++k) {
            int j0 = jpk[k] & 0xffff;
            int j1 = jpk[k] >> 16;
            pk[k] = r0[j0] | (r0[j1] << 8) | (r1[j0] << 16) | (r1[j1] << 24);
        }
        s_pk[e] = make_int4(pk[0], pk[1], pk[2], pk[3]);
    }
    __syncthreads();

    // hoist this thread's 4 tasks into registers (n-independent)
    int4   P[4];
    float4 F[4];
    float  FI[4], FI1[4];
    long long OFF[4];
    bool   HEAD[4];
    #pragma unroll
    for (int it = 0; it < 4; ++it) {
        int task = it * 256 + tid;
        int r = task >> 7;
        int s = task & 127;
        P[it]   = s_pk[task];
        F[it]   = s_fj4[s];
        FI[it]  = s_fi[r];
        FI1[it] = s_fi1[r];
        HEAD[it] = (s == 0);
        OFF[it] = ((long long)r << 9) + (HEAD[it] ? 0 : (4 * s - 1));
    }

    long long base = 1LL + ((long long)b << 24) + ((long long)(ic * 8) << 9);

    for (int n = 0; n < 64; ++n) {
        float* pbase = out + base + ((long long)n << 18);
        #pragma unroll
        for (int it = 0; it < 4; ++it) {
            int4 p4 = P[it];
            float4 f4 = F[it];
            float fi = FI[it], fi1 = FI1[it];
            int pks[4] = { p4.x, p4.y, p4.z, p4.w };
            float fjs[4] = { f4.x, f4.y, f4.z, f4.w };
            float v[4];
            #pragma unroll
            for (int k = 0; k < 4; ++k) {
                int p = pks[k];
                float Pv = (((p      ) & 255) == n ? fi1 : 0.f)
                         + (((p >> 16) & 255) == n ? fi  : 0.f);
                float Qv = (((p >>  8) & 255) == n ? fi1 : 0.f)
                         + (((p >> 24) & 255) == n ? fi  : 0.f);
                v[k] = Pv + fjs[k] * (Qv - Pv);
            }
            float* dst = pbase + OFF[it];
            if (HEAD[it]) {
                dst[0] = v[0]; dst[1] = v[1]; dst[2] = v[2]; dst[511] = v[3];
            } else {
                *(float4*)dst = make_float4(v[0], v[1], v[2], v[3]);
            }
        }
    }
}

// ---------------------------------------------------------------------------
extern "C" void kernel_launch(void* const* d_in, const int* in_sizes, int n_in,
                              void* d_out, int out_size, void* d_ws, size_t ws_size,
                              hipStream_t stream)
{
    const float* code     = (const float*)d_in[0];   // [8,768,32,32]
    const float* clusters = (const float*)d_in[1];   // [64,768]
    float* out = (float*)d_out;                      // [loss | resized | code]
    float* nc_t = (float*)d_ws;                      // 768*64 floats, [c][n]
    int* assign = (int*)((char*)d_ws + 196608);      // 8192 ints

    k_norm   <<<NCL,                         256, 0, stream>>>(clusters, code, nc_t, out);
    k_assign <<<256,                         256, 0, stream>>>(code, nc_t, assign, out);
    k_dense2 <<<DENSE2_BLOCKS + COPY_BLOCKS, 256, 0, stream>>>(assign, code, out);
}